// Round 3
// baseline (3052.200 us; speedup 1.0000x reference)
//
#include <hip/hip_runtime.h>
#include <stdint.h>

#define TT 512
#define BB 64
#define DD 1024
#define HH 1024

typedef float  f32x4   __attribute__((ext_vector_type(4)));
typedef float  float4v __attribute__((ext_vector_type(4)));
typedef short  bf16x8  __attribute__((ext_vector_type(8)));
typedef short  short4v __attribute__((ext_vector_type(4)));
typedef unsigned long long u64;

__device__ __forceinline__ short f2bf(float x) {
  uint32_t u = __builtin_bit_cast(uint32_t, x);
  u += 0x7fffu + ((u >> 16) & 1u);   // RNE to bf16
  return (short)(u >> 16);
}
__device__ __forceinline__ float bf2f(short s) {
  uint32_t u = ((uint32_t)(uint16_t)s) << 16;
  return __builtin_bit_cast(float, u);
}

// MALL-coherent (agent-scope, L1/L2-bypassing) accesses — no cache flushes.
__device__ __forceinline__ u64 aload(const u64* p) {
  return __hip_atomic_load(p, __ATOMIC_RELAXED, __HIP_MEMORY_SCOPE_AGENT);
}
__device__ __forceinline__ void astore(u64* p, u64 v) {
  __hip_atomic_store(p, v, __ATOMIC_RELAXED, __HIP_MEMORY_SCOPE_AGENT);
}

union HU { u64 q[2]; bf16x8 v; };

// ---------------- W transpose + hi/lo split: W[k][n] f32 -> Wt_hi/lo[n][k] bf16 ----
__global__ __launch_bounds__(256) void k_wsplit(
    const float* __restrict__ Wih, const float* __restrict__ Whh,
    short* __restrict__ ih_hi, short* __restrict__ ih_lo,
    short* __restrict__ hh_hi, short* __restrict__ hh_lo)
{
  __shared__ float tile[64][65];
  int bid = blockIdx.x;
  int z = bid >> 8;              // 0: W_ih, 1: W_hh
  int tt = bid & 255;
  int tk = tt >> 4, tn = tt & 15;
  const float* __restrict__ src = z ? Whh : Wih;
  short* __restrict__ dhi = z ? hh_hi : ih_hi;
  short* __restrict__ dlo = z ? hh_lo : ih_lo;
  int k0 = tk * 64, n0 = tn * 64;
  int tid = threadIdx.x;
  #pragma unroll
  for (int i = 0; i < 4; ++i) {
    int idx = tid + i * 256;
    int r = idx >> 4, c4 = (idx & 15) * 4;
    float4v v = *reinterpret_cast<const float4v*>(&src[(size_t)(k0 + r) * HH + n0 + c4]);
    tile[r][c4 + 0] = v[0]; tile[r][c4 + 1] = v[1];
    tile[r][c4 + 2] = v[2]; tile[r][c4 + 3] = v[3];
  }
  __syncthreads();
  #pragma unroll
  for (int i = 0; i < 4; ++i) {
    int idx = tid + i * 256;
    int n = idx >> 4, kq = (idx & 15) * 4;
    short4v vh, vl;
    #pragma unroll
    for (int j = 0; j < 4; ++j) {
      float x = tile[kq + j][n];
      short h = f2bf(x);
      vh[j] = h;
      vl[j] = f2bf(x - bf2f(h));
    }
    *reinterpret_cast<short4v*>(&dhi[(size_t)(n0 + n) * 1024 + k0 + kq]) = vh;
    *reinterpret_cast<short4v*>(&dlo[(size_t)(n0 + n) * 1024 + k0 + kq]) = vl;
  }
}

// ---------------- x_proj GEMM: [32768 x 1024] = input @ W_ih + bias --------------
__global__ __launch_bounds__(256, 2) void k_gemm_xp(
    const float* __restrict__ A, const short* __restrict__ Bt_hi,
    const short* __restrict__ Bt_lo, const float* __restrict__ bias,
    float* __restrict__ xp)
{
  __shared__ __align__(16) short Ah[4096];
  __shared__ __align__(16) short Al[4096];
  __shared__ __align__(16) short Bh[4096];
  __shared__ __align__(16) short Bl[4096];
  int bid = blockIdx.x;
  int mb = bid & 255, nb = bid >> 8;
  size_t m0 = (size_t)mb * 128;
  int n0 = nb * 128;
  int tid = threadIdx.x;
  int lane = tid & 63, wid = tid >> 6;
  int wm = wid >> 1, wn = wid & 1;
  int lr = lane & 15, lk = lane >> 4;

  f32x4 acc[4][4];
  #pragma unroll
  for (int mt = 0; mt < 4; ++mt)
    #pragma unroll
    for (int nt = 0; nt < 4; ++nt) {
      acc[mt][nt][0] = 0.f; acc[mt][nt][1] = 0.f;
      acc[mt][nt][2] = 0.f; acc[mt][nt][3] = 0.f;
    }

  for (int kt = 0; kt < 32; ++kt) {
    int k0 = kt * 32;
    __syncthreads();
    #pragma unroll
    for (int i = 0; i < 4; ++i) {
      int idx = tid + i * 256;
      int r = idx >> 3, q = idx & 7;
      float4v v = *reinterpret_cast<const float4v*>(&A[(m0 + r) * 1024 + k0 + q * 4]);
      short4v vh, vl;
      #pragma unroll
      for (int j = 0; j < 4; ++j) {
        short h = f2bf(v[j]);
        vh[j] = h;
        vl[j] = f2bf(v[j] - bf2f(h));
      }
      int off = ((q >> 1) * 128 + r) * 8 + (q & 1) * 4;
      *reinterpret_cast<short4v*>(&Ah[off]) = vh;
      *reinterpret_cast<short4v*>(&Al[off]) = vl;
    }
    {
      int n = tid >> 1, half = tid & 1;
      size_t gb = (size_t)(n0 + n) * 1024 + k0 + half * 16;
      bf16x8 h0 = *reinterpret_cast<const bf16x8*>(&Bt_hi[gb]);
      bf16x8 h1 = *reinterpret_cast<const bf16x8*>(&Bt_hi[gb + 8]);
      bf16x8 l0 = *reinterpret_cast<const bf16x8*>(&Bt_lo[gb]);
      bf16x8 l1 = *reinterpret_cast<const bf16x8*>(&Bt_lo[gb + 8]);
      int kb = half * 2;
      *reinterpret_cast<bf16x8*>(&Bh[(kb * 128 + n) * 8]) = h0;
      *reinterpret_cast<bf16x8*>(&Bh[((kb + 1) * 128 + n) * 8]) = h1;
      *reinterpret_cast<bf16x8*>(&Bl[(kb * 128 + n) * 8]) = l0;
      *reinterpret_cast<bf16x8*>(&Bl[((kb + 1) * 128 + n) * 8]) = l1;
    }
    __syncthreads();

    bf16x8 a_h[4], a_l[4], b_h[4], b_l[4];
    #pragma unroll
    for (int mt = 0; mt < 4; ++mt) {
      int off = (lk * 128 + wm * 64 + mt * 16 + lr) * 8;
      a_h[mt] = *reinterpret_cast<const bf16x8*>(&Ah[off]);
      a_l[mt] = *reinterpret_cast<const bf16x8*>(&Al[off]);
    }
    #pragma unroll
    for (int nt = 0; nt < 4; ++nt) {
      int off = (lk * 128 + wn * 64 + nt * 16 + lr) * 8;
      b_h[nt] = *reinterpret_cast<const bf16x8*>(&Bh[off]);
      b_l[nt] = *reinterpret_cast<const bf16x8*>(&Bl[off]);
    }
    #pragma unroll
    for (int mt = 0; mt < 4; ++mt)
      #pragma unroll
      for (int nt = 0; nt < 4; ++nt) {
        acc[mt][nt] = __builtin_amdgcn_mfma_f32_16x16x32_bf16(a_h[mt], b_h[nt], acc[mt][nt], 0, 0, 0);
        acc[mt][nt] = __builtin_amdgcn_mfma_f32_16x16x32_bf16(a_h[mt], b_l[nt], acc[mt][nt], 0, 0, 0);
        acc[mt][nt] = __builtin_amdgcn_mfma_f32_16x16x32_bf16(a_l[mt], b_h[nt], acc[mt][nt], 0, 0, 0);
      }
  }
  #pragma unroll
  for (int nt = 0; nt < 4; ++nt) {
    int col = n0 + wn * 64 + nt * 16 + lr;
    float bv = bias[col];
    #pragma unroll
    for (int mt = 0; mt < 4; ++mt)
      #pragma unroll
      for (int r = 0; r < 4; ++r) {
        size_t row = m0 + wm * 64 + mt * 16 + lk * 4 + r;
        xp[row * 1024 + col] = acc[mt][nt][r] + bv;
      }
  }
}

// ---------------- pack init_state into h plane layout [g][kb128][row16][8] --------
__global__ __launch_bounds__(256) void k_init_h(
    const float* __restrict__ init, short* __restrict__ hhi, short* __restrict__ hlo)
{
  int i = blockIdx.x * 256 + threadIdx.x;   // 0..65535
  float v = init[i];
  int b = i >> 10, n = i & 1023;
  int g = b >> 4, row = b & 15, kb = n >> 3, e = n & 7;
  size_t off = ((size_t)(g * 128 + kb) * 16 + row) * 8 + e;
  short h = f2bf(v);
  hhi[off] = h;
  hlo[off] = f2bf(v - bf2f(h));
}

// ---------------- persistent recurrence: 512 steps, 4 groups x 32 WGs ------------
// W_hh slice in REGISTERS (128 VGPR/lane); wave = K-quarter (both N-tiles);
// h handoff via MALL-coherent u64 stores; per-wave subflag signaling.
__global__ __launch_bounds__(256, 1) void k_rnn(
    const float* __restrict__ xp,
    const short* __restrict__ whh_hi, const short* __restrict__ whh_lo,
    u64* __restrict__ hhi64, u64* __restrict__ hlo64,
    unsigned* __restrict__ flags, float* __restrict__ out)
{
  __shared__ __align__(16) short Wh[32768];   // one-time staging only
  __shared__ __align__(16) short Wl[32768];
  __shared__ __align__(16) float red[6 * 64 * 4];   // [j=kh-1 x nt][lane][4]
  __shared__ __align__(16) float stage[512];        // [row16][col32]

  int bid = blockIdx.x;
  int g = bid & 3;               // batch-row group: rows g*16..+16
  int w = bid >> 2;              // 0..31: column slice
  int c0 = w * 32;
  int tid = threadIdx.x;
  int lane = tid & 63;
  int kh = tid >> 6;             // wave = K-quarter (8 ksteps)
  int lr = lane & 15, lk = lane >> 4;

  // one-time: stage W slice fragment-major into LDS
  {
    int combo = tid >> 1, ksh = tid & 1;
    int colw = combo >> 2, lkf = combo & 3;
    int ntf = colw >> 4, lrf = colw & 15;
    #pragma unroll
    for (int j = 0; j < 16; ++j) {
      int kstep = ksh * 16 + j;
      int dst = ((ntf * 32 + kstep) * 64 + lrf * 4 + lkf) * 8;
      size_t src = (size_t)(c0 + colw) * 1024 + kstep * 32 + lkf * 8;
      *reinterpret_cast<bf16x8*>(&Wh[dst]) = *reinterpret_cast<const bf16x8*>(&whh_hi[src]);
      *reinterpret_cast<bf16x8*>(&Wl[dst]) = *reinterpret_cast<const bf16x8*>(&whh_lo[src]);
    }
  }
  __syncthreads();
  // one-time: wave's K-quarter of W (both N-tiles) into registers
  bf16x8 w_h[8][2], w_l[8][2];
  #pragma unroll
  for (int ks = 0; ks < 8; ++ks) {
    int kstep = kh * 8 + ks;
    #pragma unroll
    for (int nt = 0; nt < 2; ++nt) {
      int boff = ((nt * 32 + kstep) * 64 + lr * 4 + lk) * 8;
      w_h[ks][nt] = *reinterpret_cast<const bf16x8*>(&Wh[boff]);
      w_l[ks][nt] = *reinterpret_cast<const bf16x8*>(&Wl[boff]);
    }
  }

  unsigned* fl = flags + g * 64;
  for (int t = 0; t < TT; ++t) {
    // xp prefetch (independent of h) before the poll
    float xpv[2][4];
    if (kh == 0) {
      #pragma unroll
      for (int nt = 0; nt < 2; ++nt)
        #pragma unroll
        for (int r = 0; r < 4; ++r)
          xpv[nt][r] = xp[((size_t)t * 64 + g * 16 + lk * 4 + r) * 1024 + c0 + nt * 16 + lr];
    }
    if (t > 0) {
      // all 4 waves poll independently: 64 lanes x 64 subflags, then straight
      // to this wave's own A-loads (no pre-load barrier).
      int ok;
      do {
        unsigned v = __hip_atomic_load(&fl[lane], __ATOMIC_RELAXED,
                                       __HIP_MEMORY_SCOPE_AGENT);
        ok = ((int)v >= t);
      } while (!__all(ok));
    }
    const u64* hhq = hhi64 + (size_t)(t & 1) * 16384;
    const u64* hlq = hlo64 + (size_t)(t & 1) * 16384;
    f32x4 acc[2][2];
    #pragma unroll
    for (int nt = 0; nt < 2; ++nt)
      #pragma unroll
      for (int p = 0; p < 2; ++p) {
        acc[nt][p][0] = 0.f; acc[nt][p][1] = 0.f;
        acc[nt][p][2] = 0.f; acc[nt][p][3] = 0.f;
      }
    #pragma unroll
    for (int ks = 0; ks < 8; ++ks) {
      int kstep = kh * 8 + ks;
      int kb = kstep * 4 + lk;
      size_t ai = ((size_t)(g * 128 + kb) * 16 + lr) * 2;
      HU ua, ul;
      ua.q[0] = aload(hhq + ai); ua.q[1] = aload(hhq + ai + 1);
      ul.q[0] = aload(hlq + ai); ul.q[1] = aload(hlq + ai + 1);
      int p = ks & 1;
      #pragma unroll
      for (int nt = 0; nt < 2; ++nt) {
        acc[nt][p] = __builtin_amdgcn_mfma_f32_16x16x32_bf16(ua.v, w_h[ks][nt], acc[nt][p], 0, 0, 0);
        acc[nt][p] = __builtin_amdgcn_mfma_f32_16x16x32_bf16(ua.v, w_l[ks][nt], acc[nt][p], 0, 0, 0);
        acc[nt][p] = __builtin_amdgcn_mfma_f32_16x16x32_bf16(ul.v, w_h[ks][nt], acc[nt][p], 0, 0, 0);
      }
    }
    if (kh != 0) {
      #pragma unroll
      for (int nt = 0; nt < 2; ++nt) {
        f32x4 s;
        #pragma unroll
        for (int r = 0; r < 4; ++r) s[r] = acc[nt][0][r] + acc[nt][1][r];
        *reinterpret_cast<f32x4*>(&red[(((kh - 1) * 2 + nt) * 64 + lane) * 4]) = s;
      }
    }
    __syncthreads();                       // barrier1: red ready
    if (kh == 0) {
      #pragma unroll
      for (int nt = 0; nt < 2; ++nt) {
        f32x4 s;
        #pragma unroll
        for (int r = 0; r < 4; ++r) s[r] = acc[nt][0][r] + acc[nt][1][r];
        #pragma unroll
        for (int j = 0; j < 3; ++j) {
          f32x4 rv = *reinterpret_cast<const f32x4*>(&red[((j * 2 + nt) * 64 + lane) * 4]);
          #pragma unroll
          for (int r = 0; r < 4; ++r) s[r] += rv[r];
        }
        #pragma unroll
        for (int r = 0; r < 4; ++r) {
          float x = s[r] + xpv[nt][r];
          float ex = __expf(2.0f * x);     // tanh = 1 - 2/(e^2x + 1)
          stage[(lk * 4 + r) * 32 + nt * 16 + lr] = 1.0f - 2.0f / (ex + 1.0f);
        }
      }
    }
    __syncthreads();                       // barrier2: stage ready
    u64* nhq = hhi64 + (size_t)((t + 1) & 1) * 16384;
    u64* nlq = hlo64 + (size_t)((t + 1) & 1) * 16384;
    if (tid < 128) {                       // waves 0,1 pack + store + signal
      int idx = tid * 4;
      int cb = idx >> 7, rem = idx & 127, row2 = rem >> 3, e = rem & 7;
      float v0 = stage[row2 * 32 + cb * 8 + e + 0];
      float v1 = stage[row2 * 32 + cb * 8 + e + 1];
      float v2 = stage[row2 * 32 + cb * 8 + e + 2];
      float v3 = stage[row2 * 32 + cb * 8 + e + 3];
      short h0 = f2bf(v0), h1 = f2bf(v1), h2 = f2bf(v2), h3 = f2bf(v3);
      short l0 = f2bf(v0 - bf2f(h0)), l1 = f2bf(v1 - bf2f(h1));
      short l2 = f2bf(v2 - bf2f(h2)), l3 = f2bf(v3 - bf2f(h3));
      u64 hw = (u64)(uint16_t)h0 | ((u64)(uint16_t)h1 << 16) |
               ((u64)(uint16_t)h2 << 32) | ((u64)(uint16_t)h3 << 48);
      u64 lw = (u64)(uint16_t)l0 | ((u64)(uint16_t)l1 << 16) |
               ((u64)(uint16_t)l2 << 32) | ((u64)(uint16_t)l3 << 48);
      size_t off = ((size_t)(g * 128 + w * 4 + cb) * 16 + row2) * 2 + (e >> 2);
      astore(nhq + off, hw);
      astore(nlq + off, lw);
      if (t == TT - 1) {
        size_t o = (size_t)(g * 16 + row2) * 1024 + c0 + cb * 8 + e;
        float4v ov; ov[0] = v0; ov[1] = v1; ov[2] = v2; ov[3] = v3;
        *reinterpret_cast<float4v*>(&out[o]) = ov;
        *reinterpret_cast<float4v*>(&out[65536 + o]) = ov;
      }
      // drain own stores, then fire-and-forget this wave's subflag
      asm volatile("s_waitcnt vmcnt(0)" ::: "memory");
      if (lane == 0)
        __hip_atomic_store(&fl[w * 2 + kh], (unsigned)(t + 1), __ATOMIC_RELAXED,
                           __HIP_MEMORY_SCOPE_AGENT);
    }
  }
}

extern "C" void kernel_launch(void* const* d_in, const int* in_sizes, int n_in,
                              void* d_out, int out_size, void* d_ws, size_t ws_size,
                              hipStream_t stream) {
  (void)in_sizes; (void)n_in; (void)out_size; (void)ws_size;
  const float* input      = (const float*)d_in[0];
  const float* init_state = (const float*)d_in[1];
  const float* W_ih       = (const float*)d_in[2];
  const float* W_hh       = (const float*)d_in[3];
  const float* bias       = (const float*)d_in[4];
  float* out = (float*)d_out;

  char* ws = (char*)d_ws;
  float* xp = (float*)ws;
  size_t off = (size_t)TT * BB * HH * 4;                 // 134.2 MB x_proj
  short* ih_hi = (short*)(ws + off); off += (size_t)DD * HH * 2;
  short* ih_lo = (short*)(ws + off); off += (size_t)DD * HH * 2;
  short* hh_hi = (short*)(ws + off); off += (size_t)HH * HH * 2;
  short* hh_lo = (short*)(ws + off); off += (size_t)HH * HH * 2;
  u64*   h_hi  = (u64*)(ws + off);   off += (size_t)2 * 16384 * 8;
  u64*   h_lo  = (u64*)(ws + off);   off += (size_t)2 * 16384 * 8;
  unsigned* flags = (unsigned*)(ws + off); off += (size_t)256 * 4;

  hipMemsetAsync(flags, 0, 256 * 4, stream);
  k_wsplit<<<512, 256, 0, stream>>>(W_ih, W_hh, ih_hi, ih_lo, hh_hi, hh_lo);
  k_gemm_xp<<<2048, 256, 0, stream>>>(input, ih_hi, ih_lo, bias, xp);
  k_init_h<<<256, 256, 0, stream>>>(init_state, (short*)h_hi, (short*)h_lo);
  k_rnn<<<128, 256, 0, stream>>>(xp, hh_hi, hh_lo, h_hi, h_lo, flags, out);
}